// Round 1
// baseline (276.094 us; speedup 1.0000x reference)
//
#include <hip/hip_runtime.h>
#include <math.h>

#define N 8192
#define D 64
#define BI 32      // i-rows per block
#define TJ 64      // j-rows per LDS tile
#define NT 512     // threads per block (16 j-groups x 32 i-lanes)

// Kernel 0: squared norm of each row. One wave (64 lanes) per row, D=64 -> one elem/lane.
__global__ __launch_bounds__(256) void row_norms_kernel(const float* __restrict__ x,
                                                        float* __restrict__ norms) {
    const int wave = threadIdx.x >> 6;
    const int lane = threadIdx.x & 63;
    const int row  = blockIdx.x * 4 + wave;
    const float v = x[row * D + lane];
    float s = v * v;
#pragma unroll
    for (int off = 32; off >= 1; off >>= 1) s += __shfl_xor(s, off);
    if (lane == 0) norms[row] = s;
}

// Main kernel: each block handles BI consecutive i-rows; sweeps all j in TJ tiles.
// Thread t: i_local = t & 31 (x_i in registers), j-group jg = t >> 5 (handles TJ/16 j per tile).
__global__ __launch_bounds__(NT) void knn_main_kernel(const float* __restrict__ x,
                                                      const float* __restrict__ norms,
                                                      float* __restrict__ block_sums) {
    __shared__ float s_xj[TJ * D];     // 16 KB
    __shared__ float s_nj[TJ];
    __shared__ float s_d1[16][BI];
    __shared__ float s_d2[16][BI];
    __shared__ float s_se[16][BI];

    const int t  = threadIdx.x;
    const int il = t & (BI - 1);
    const int jg = t >> 5;             // 0..15
    const int i  = blockIdx.x * BI + il;

    // x_i into registers (fully unrolled -> static indices -> VGPRs)
    float xi[D];
#pragma unroll
    for (int d0 = 0; d0 < D; d0 += 4) {
        const float4 v = *reinterpret_cast<const float4*>(x + i * D + d0);
        xi[d0 + 0] = v.x; xi[d0 + 1] = v.y; xi[d0 + 2] = v.z; xi[d0 + 3] = v.w;
    }
    const float ni = norms[i];

    float d1 = 3.0e38f, d2 = 3.0e38f;  // two smallest distances (excl. self)
    float sumexp = 0.0f;               // sum_j != i exp(-d_ij)

    for (int j0 = 0; j0 < N; j0 += TJ) {
        __syncthreads();
        {   // stage TJ rows (TJ*D floats = 1024 float4, NT=512 -> 2 each), coalesced
            const float4* src = reinterpret_cast<const float4*>(x + j0 * D);
            float4* dst = reinterpret_cast<float4*>(s_xj);
            dst[t]      = src[t];
            dst[t + NT] = src[t + NT];
            if (t < TJ) s_nj[t] = norms[j0 + t];
        }
        __syncthreads();

#pragma unroll
        for (int jj = 0; jj < TJ / 16; ++jj) {
            const int jl = jg * (TJ / 16) + jj;
            const float* xjp = s_xj + jl * D;
            float dot = 0.0f;
#pragma unroll
            for (int d0 = 0; d0 < D; d0 += 4) {
                const float4 v = *reinterpret_cast<const float4*>(xjp + d0);
                dot = fmaf(xi[d0 + 0], v.x, dot);
                dot = fmaf(xi[d0 + 1], v.y, dot);
                dot = fmaf(xi[d0 + 2], v.z, dot);
                dot = fmaf(xi[d0 + 3], v.w, dot);
            }
            const int j = j0 + jl;
            if (j != i) {
                const float sq   = fmaxf(ni + s_nj[jl] - 2.0f * dot, 0.0f);
                const float dist = sqrtf(sq);
                sumexp += expf(-dist);
                if (dist < d2) {
                    if (dist < d1) { d2 = d1; d1 = dist; }
                    else           { d2 = dist; }
                }
            }
        }
    }

    s_d1[jg][il] = d1; s_d2[jg][il] = d2; s_se[jg][il] = sumexp;
    __syncthreads();

    if (t < BI) {   // lanes 0..31 of wave 0: merge the 16 j-groups for i_local = t
        float a1 = s_d1[0][t], a2 = s_d2[0][t], se = s_se[0][t];
#pragma unroll
        for (int g = 1; g < 16; ++g) {
            const float b1 = s_d1[g][t], b2 = s_d2[g][t];
            const float lo = fminf(a1, b1);
            const float hi = fminf(fmaxf(a1, b1), fminf(a2, b2));
            a1 = lo; a2 = hi;
            se += s_se[g][t];
        }
        float pp = 0.5f * (a1 + a2) + logf(se);   // mean of top-2 dists + log denom
#pragma unroll
        for (int off = 16; off >= 1; off >>= 1) pp += __shfl_xor(pp, off);
        if (t == 0) block_sums[blockIdx.x] = pp;
    }
}

__global__ __launch_bounds__(64) void finalize_kernel(const float* __restrict__ block_sums,
                                                      float* __restrict__ out) {
    const int t = threadIdx.x;
    float v = block_sums[t] + block_sums[t + 64] + block_sums[t + 128] + block_sums[t + 192];
#pragma unroll
    for (int off = 32; off >= 1; off >>= 1) v += __shfl_xor(v, off);
    if (t == 0) out[0] = v * (1.0f / (float)N);
}

extern "C" void kernel_launch(void* const* d_in, const int* in_sizes, int n_in,
                              void* d_out, int out_size, void* d_ws, size_t ws_size,
                              hipStream_t stream) {
    const float* x = (const float*)d_in[0];
    float* out = (float*)d_out;
    float* norms      = (float*)d_ws;        // N floats
    float* block_sums = norms + N;           // N/BI = 256 floats

    row_norms_kernel<<<N / 4, 256, 0, stream>>>(x, norms);
    knn_main_kernel<<<N / BI, NT, 0, stream>>>(x, norms, block_sums);
    finalize_kernel<<<1, 64, 0, stream>>>(block_sums, out);
}

// Round 2
// 66.447 us; speedup vs baseline: 4.1551x; 4.1551x over previous
//
#include <hip/hip_runtime.h>
#include <math.h>

#define N 8192
#define D 64
#define NTILES (N / 32)            // 256 i-tiles
#define JSPLIT 2
#define JPANEL 256                 // j rows staged per iteration
#define ITERS (N / JSPLIT / JPANEL) // 16
#define WAVES 8

typedef short bf16x8 __attribute__((ext_vector_type(8)));
typedef float f32x16 __attribute__((ext_vector_type(16)));

// round-to-nearest-even f32 -> bf16 bits
static __device__ __forceinline__ unsigned short f2bf(float f) {
    unsigned int u = __float_as_uint(f);
    return (unsigned short)((u + 0x7fffu + ((u >> 16) & 1u)) >> 16);
}

// xb fragment layout: 16B slot s = (tile*4 + kk)*64 + l, holding 8 bf16.
// element (row r, dim k): tile=r>>5, kk=k>>4, hi=(k>>3)&1, l=(r&31)+32*hi, e=k&7
// => for a 32-row tile, MFMA operand for K-step kk is slot[(tile*4+kk)*64 + lane]
//    (lane l holds row (l&31), k = kk*16 + 8*(l>>5) + 0..7) — linear in lane.

__global__ __launch_bounds__(256) void prep_kernel(const float* __restrict__ x,
                                                   unsigned short* __restrict__ xb,
                                                   float* __restrict__ norms) {
    const int u = blockIdx.x * 256 + threadIdx.x;   // unit = (row, octet)
    const int r = u >> 3, oct = u & 7;
    const float4 v0 = *(const float4*)(x + r * D + oct * 8);
    const float4 v1 = *(const float4*)(x + r * D + oct * 8 + 4);
    float s = v0.x * v0.x + v0.y * v0.y + v0.z * v0.z + v0.w * v0.w
            + v1.x * v1.x + v1.y * v1.y + v1.z * v1.z + v1.w * v1.w;
    s += __shfl_xor(s, 1); s += __shfl_xor(s, 2); s += __shfl_xor(s, 4);
    if (oct == 0) norms[r] = s;
    uint4 wv;
    wv.x = (unsigned)f2bf(v0.x) | ((unsigned)f2bf(v0.y) << 16);
    wv.y = (unsigned)f2bf(v0.z) | ((unsigned)f2bf(v0.w) << 16);
    wv.z = (unsigned)f2bf(v1.x) | ((unsigned)f2bf(v1.y) << 16);
    wv.w = (unsigned)f2bf(v1.z) | ((unsigned)f2bf(v1.w) << 16);
    const int slot = ((r >> 5) * 4 + (oct >> 1)) * 64 + (r & 31) + 32 * (oct & 1);
    *(uint4*)(xb + slot * 8) = wv;
}

__global__ __launch_bounds__(512, 4) void knn_mfma_kernel(
        const unsigned short* __restrict__ xb,
        const float* __restrict__ norms,
        float* __restrict__ partials) {
    __shared__ uint4 s_xj[2048];          // 32 KB: 8 j-tiles x 4 kk x 64 lanes
    __shared__ float s_nj[JPANEL];        // 1 KB
    __shared__ float s_red[WAVES * 96];   // 3 KB

    const int t = threadIdx.x;
    const int w = t >> 6, lane = t & 63;
    const int itile = blockIdx.x >> 1, h = blockIdx.x & 1;
    const int i = itile * 32 + (lane & 31);
    const float ni = norms[i];

    bf16x8 xi[4];
#pragma unroll
    for (int kk = 0; kk < 4; ++kk)
        xi[kk] = *(const bf16x8*)(xb + ((itile * 4 + kk) * 64 + lane) * 8);

    float d1 = 3.0e38f, d2 = 3.0e38f, se = 0.0f;
    const int hi = lane >> 5;

    for (int it = 0; it < ITERS; ++it) {
        const int jbase = h * (N / JSPLIT) + it * JPANEL;
        __syncthreads();
        // stage 256 j-rows (32 KB) of fragment-order bf16, linear copy
#pragma unroll
        for (int p = 0; p < 4; ++p) {
            const int c = p * 8 + w;  // chunk: 64 slots = 1 KB, wave-uniform LDS base
            const unsigned short* g = xb + ((size_t)jbase * 8 + c * 64 + lane) * 8;
            __builtin_amdgcn_global_load_lds(
                (const __attribute__((address_space(1))) unsigned int*)g,
                (__attribute__((address_space(3))) unsigned int*)(s_xj + c * 64),
                16, 0, 0);
        }
        if (t < JPANEL) s_nj[t] = norms[jbase + t];
        __syncthreads();   // compiler drains vmcnt before s_barrier

        const int jt = w * 32;  // this wave's j-tile within the panel
        f32x16 acc;
#pragma unroll
        for (int q = 0; q < 16; ++q) acc[q] = 0.0f;
#pragma unroll
        for (int kk = 0; kk < 4; ++kk) {
            const bf16x8 aj = *(const bf16x8*)(s_xj + (w * 4 + kk) * 64 + lane);
            acc = __builtin_amdgcn_mfma_f32_32x32x16_bf16(aj, xi[kk], acc, 0, 0, 0);
        }
        // epilogue: D[m][n] = dot(x_{jbase+jt+m}, x_i), col n = lane&31,
        // row m = (reg&3) + 8*(reg>>2) + 4*(lane>>5)
#pragma unroll
        for (int q = 0; q < 4; ++q) {
            const int rbase = 8 * q + 4 * hi;
            const float4 nj4 = *(const float4*)(s_nj + jt + rbase);
            const int jg = jbase + jt + rbase;
#pragma unroll
            for (int b = 0; b < 4; ++b) {
                const float dot = acc[q * 4 + b];
                float sq = fmaxf(ni + ((const float*)&nj4)[b] - 2.0f * dot, 0.0f);
                float dd = sqrtf(sq);
                float e = __expf(-dd);
                if (jg + b == i) { e = 0.0f; dd = 3.0e38f; }  // self pair
                se += e;
                d2 = fminf(d2, fmaxf(d1, dd));
                d1 = fminf(d1, dd);
            }
        }
    }

    // merge lane <-> lane^32 (same i, disjoint j rows)
    {
        const float o1 = __shfl_xor(d1, 32);
        const float o2 = __shfl_xor(d2, 32);
        const float os = __shfl_xor(se, 32);
        const float n1 = fminf(d1, o1);
        const float n2 = fminf(fmaxf(d1, o1), fminf(d2, o2));
        d1 = n1; d2 = n2; se += os;
    }
    __syncthreads();
    if (lane < 32) {
        s_red[w * 96 + lane] = d1;
        s_red[w * 96 + 32 + lane] = d2;
        s_red[w * 96 + 64 + lane] = se;
    }
    __syncthreads();
    if (t < 32) {
        float a1 = s_red[t], a2 = s_red[32 + t], as = s_red[64 + t];
#pragma unroll
        for (int g = 1; g < WAVES; ++g) {
            const float b1 = s_red[g * 96 + t], b2 = s_red[g * 96 + 32 + t];
            const float m1 = fminf(a1, b1);
            const float m2 = fminf(fmaxf(a1, b1), fminf(a2, b2));
            a1 = m1; a2 = m2; as += s_red[g * 96 + 64 + t];
        }
        float* P = partials + blockIdx.x * 96;
        P[t] = a1; P[32 + t] = a2; P[64 + t] = as;
    }
}

__global__ __launch_bounds__(1024) void merge_kernel(const float* __restrict__ partials,
                                                     float* __restrict__ out) {
    __shared__ float s_sum[16];
    const int t = threadIdx.x;
    float sum = 0.0f;
#pragma unroll
    for (int it = 0; it < 8; ++it) {
        const int p = t + it * 1024;          // point index
        const int itile = p >> 5, il = p & 31;
        const float* A = partials + (itile * 2) * 96;
        const float* B = A + 96;
        const float a1 = A[il], a2 = A[32 + il], as = A[64 + il];
        const float b1 = B[il], b2 = B[32 + il], bs = B[64 + il];
        const float m1 = fminf(a1, b1);
        const float m2 = fminf(fmaxf(a1, b1), fminf(a2, b2));
        sum += 0.5f * (m1 + m2) + logf(as + bs);
    }
#pragma unroll
    for (int off = 32; off >= 1; off >>= 1) sum += __shfl_xor(sum, off);
    if ((t & 63) == 0) s_sum[t >> 6] = sum;
    __syncthreads();
    if (t == 0) {
        float tot = 0.0f;
#pragma unroll
        for (int g = 0; g < 16; ++g) tot += s_sum[g];
        out[0] = tot * (1.0f / (float)N);
    }
}

extern "C" void kernel_launch(void* const* d_in, const int* in_sizes, int n_in,
                              void* d_out, int out_size, void* d_ws, size_t ws_size,
                              hipStream_t stream) {
    const float* x = (const float*)d_in[0];
    float* out = (float*)d_out;
    char* ws = (char*)d_ws;
    unsigned short* xb = (unsigned short*)ws;              // 1 MB bf16 fragments
    float* norms = (float*)(ws + (size_t)N * D * 2);       // 32 KB
    float* partials = norms + N;                           // 512*96 f32 = 192 KB

    prep_kernel<<<(N * 8) / 256, 256, 0, stream>>>(x, xb, norms);
    knn_mfma_kernel<<<NTILES * JSPLIT, 512, 0, stream>>>(xb, norms, partials);
    merge_kernel<<<1, 1024, 0, stream>>>(partials, out);
}

// Round 3
// 38.944 us; speedup vs baseline: 7.0895x; 1.7062x over previous
//
#include <hip/hip_runtime.h>
#include <math.h>

#define N 8192
#define D 64
#define JSPLIT 4
#define ITW 16                       // j-tiles per wave: 256 tiles / (JSPLIT*4 waves)
#define C2 2.0813689810056077f       // (log2 e)^2
#define NEG2C2 -4.1627379620112154f  // -2*C2
#define LN2 0.6931471805599453f

typedef short bf16x8 __attribute__((ext_vector_type(8)));
typedef float f32x16 __attribute__((ext_vector_type(16)));
typedef float f32x4  __attribute__((ext_vector_type(4)));

static __device__ __forceinline__ unsigned short f2bf(float f) {
    unsigned int u = __float_as_uint(f);
    return (unsigned short)((u + 0x7fffu + ((u >> 16) & 1u)) >> 16);
}

// xb fragment layout (validated r2): 16B slot s = (tile*4 + kk)*64 + l;
// lane l holds row (l&31), k = kk*16 + 8*(l>>5) + 0..7.
__global__ __launch_bounds__(256) void prep_kernel(const float* __restrict__ x,
                                                   unsigned short* __restrict__ xb,
                                                   float* __restrict__ cn) {
    const int u = blockIdx.x * 256 + threadIdx.x;
    const int r = u >> 3, oct = u & 7;
    const float4 v0 = *(const float4*)(x + r * D + oct * 8);
    const float4 v1 = *(const float4*)(x + r * D + oct * 8 + 4);
    float s = v0.x * v0.x + v0.y * v0.y + v0.z * v0.z + v0.w * v0.w
            + v1.x * v1.x + v1.y * v1.y + v1.z * v1.z + v1.w * v1.w;
    s += __shfl_xor(s, 1); s += __shfl_xor(s, 2); s += __shfl_xor(s, 4);
    if (oct == 0) cn[r] = C2 * s;
    uint4 wv;
    wv.x = (unsigned)f2bf(v0.x) | ((unsigned)f2bf(v0.y) << 16);
    wv.y = (unsigned)f2bf(v0.z) | ((unsigned)f2bf(v0.w) << 16);
    wv.z = (unsigned)f2bf(v1.x) | ((unsigned)f2bf(v1.y) << 16);
    wv.w = (unsigned)f2bf(v1.z) | ((unsigned)f2bf(v1.w) << 16);
    const int slot = ((r >> 5) * 4 + (oct >> 1)) * 64 + (r & 31) + 32 * (oct & 1);
    *(uint4*)(xb + slot * 8) = wv;
}

template<bool DIAG>
static __device__ __forceinline__ void epi(const f32x16& acc, const f32x4* cj,
                                           float cni, int hi, int il,
                                           float& d1, float& d2, float& se) {
#pragma unroll
    for (int g = 0; g < 4; ++g) {
#pragma unroll
        for (int b = 0; b < 4; ++b) {
            const int q = g * 4 + b;
            const float s  = cni + cj[g][b];
            float tq = fmaf(NEG2C2, acc[q], s);
            tq = fmaxf(tq, 0.0f);
            float dd = __builtin_amdgcn_sqrtf(tq);     // scaled dist: log2e * d
            float e  = __builtin_amdgcn_exp2f(-dd);    // exp(-d)
            if (DIAG) {
                const bool self = (8 * g + 4 * hi + b) == il;
                if (self) { e = 0.0f; dd = 3.0e38f; }
            }
            se += e;
            d2 = __builtin_amdgcn_fmed3f(d1, d2, dd);  // new 2nd-smallest
            d1 = fminf(d1, dd);
        }
    }
}

__global__ __launch_bounds__(256) void knn_mfma_kernel(
        const unsigned short* __restrict__ xb,
        const float* __restrict__ cn,
        float* __restrict__ partials) {
    __shared__ float s_red[4 * 96];

    const int t = threadIdx.x;
    const int lane = t & 63;
    const int w = __builtin_amdgcn_readfirstlane(t >> 6);
    const int itile = blockIdx.x >> 2;
    const int js = blockIdx.x & 3;
    const int il = lane & 31, hi = lane >> 5;
    const float cni = cn[itile * 32 + il];

    bf16x8 xi[4];
#pragma unroll
    for (int kk = 0; kk < 4; ++kk)
        xi[kk] = *(const bf16x8*)(xb + ((size_t)(itile * 4 + kk) * 64 + lane) * 8);

    const int jt0 = (js * 4 + w) * ITW;
    float d1 = 3.0e38f, d2 = 3.0e38f, se = 0.0f;

    bf16x8 ajA[4], ajB[4];
    f32x4  cjA[4], cjB[4];

    auto LOADT = [&](int jt, bf16x8* aj, f32x4* cj) {
        const unsigned short* base = xb + ((size_t)jt * 4 * 64 + lane) * 8;
#pragma unroll
        for (int kk = 0; kk < 4; ++kk) aj[kk] = *(const bf16x8*)(base + kk * 64 * 8);
        const float* cb = cn + jt * 32 + 4 * hi;
#pragma unroll
        for (int g = 0; g < 4; ++g) cj[g] = *(const f32x4*)(cb + 8 * g);
    };

    auto COMP = [&](int jt, const bf16x8* aj, const f32x4* cj) {
        f32x16 acc;
#pragma unroll
        for (int q = 0; q < 16; ++q) acc[q] = 0.0f;
#pragma unroll
        for (int kk = 0; kk < 4; ++kk)
            acc = __builtin_amdgcn_mfma_f32_32x32x16_bf16(aj[kk], xi[kk], acc, 0, 0, 0);
        if (jt == itile) epi<true >(acc, cj, cni, hi, il, d1, d2, se);
        else             epi<false>(acc, cj, cni, hi, il, d1, d2, se);
    };

    LOADT(jt0, ajA, cjA);
    for (int it = 0; it < ITW; it += 2) {
        LOADT(jt0 + it + 1, ajB, cjB);
        COMP(jt0 + it, ajA, cjA);
        const int nx = (it + 2 < ITW) ? it + 2 : ITW - 1;
        LOADT(jt0 + nx, ajA, cjA);
        COMP(jt0 + it + 1, ajB, cjB);
    }

    // lane <-> lane^32: same i, disjoint j rows
    {
        const float o1 = __shfl_xor(d1, 32);
        const float o2 = __shfl_xor(d2, 32);
        const float os = __shfl_xor(se, 32);
        const float n1 = fminf(d1, o1);
        const float n2 = fminf(fmaxf(d1, o1), fminf(d2, o2));
        d1 = n1; d2 = n2; se += os;
    }
    if (lane < 32) {
        s_red[w * 96 + lane]      = d1;
        s_red[w * 96 + 32 + lane] = d2;
        s_red[w * 96 + 64 + lane] = se;
    }
    __syncthreads();
    if (t < 32) {
        float a1 = s_red[t], a2 = s_red[32 + t], as = s_red[64 + t];
#pragma unroll
        for (int g = 1; g < 4; ++g) {
            const float b1 = s_red[g * 96 + t], b2 = s_red[g * 96 + 32 + t];
            const float m1 = fminf(a1, b1);
            const float m2 = fminf(fmaxf(a1, b1), fminf(a2, b2));
            a1 = m1; a2 = m2; as += s_red[g * 96 + 64 + t];
        }
        float* P = partials + (size_t)blockIdx.x * 96;
        P[t] = a1; P[32 + t] = a2; P[64 + t] = as;
    }
}

__global__ __launch_bounds__(256) void mergeA_kernel(const float* __restrict__ partials,
                                                     float* __restrict__ bsum) {
    __shared__ float s_s[4];
    const int t = threadIdx.x;
    const int p = blockIdx.x * 256 + t;
    const int itile = p >> 5, il = p & 31;
    const float* P = partials + (size_t)itile * JSPLIT * 96;
    float a1 = P[il], a2 = P[32 + il], as = P[64 + il];
#pragma unroll
    for (int js = 1; js < JSPLIT; ++js) {
        const float* Q = P + js * 96;
        const float b1 = Q[il], b2 = Q[32 + il];
        const float m1 = fminf(a1, b1);
        const float m2 = fminf(fmaxf(a1, b1), fminf(a2, b2));
        a1 = m1; a2 = m2; as += Q[64 + il];
    }
    float loss = 0.5f * LN2 * (a1 + a2) + logf(as);
#pragma unroll
    for (int off = 32; off >= 1; off >>= 1) loss += __shfl_xor(loss, off);
    if ((t & 63) == 0) s_s[t >> 6] = loss;
    __syncthreads();
    if (t == 0) bsum[blockIdx.x] = s_s[0] + s_s[1] + s_s[2] + s_s[3];
}

__global__ __launch_bounds__(64) void final_kernel(const float* __restrict__ bsum,
                                                   float* __restrict__ out) {
    const int t = threadIdx.x;
    float v = (t < 32) ? bsum[t] : 0.0f;
#pragma unroll
    for (int off = 32; off >= 1; off >>= 1) v += __shfl_xor(v, off);
    if (t == 0) out[0] = v * (1.0f / (float)N);
}

extern "C" void kernel_launch(void* const* d_in, const int* in_sizes, int n_in,
                              void* d_out, int out_size, void* d_ws, size_t ws_size,
                              hipStream_t stream) {
    const float* x = (const float*)d_in[0];
    float* out = (float*)d_out;
    char* ws = (char*)d_ws;
    unsigned short* xb = (unsigned short*)ws;               // 1 MB bf16 fragments
    float* cn = (float*)(ws + (size_t)N * D * 2);           // 32 KB scaled norms
    float* partials = cn + N;                               // 1024*96 = 384 KB
    float* bsum = partials + (size_t)(N / 32) * JSPLIT * 96; // 32 floats

    prep_kernel<<<(N * 8) / 256, 256, 0, stream>>>(x, xb, cn);
    knn_mfma_kernel<<<(N / 32) * JSPLIT, 256, 0, stream>>>(xb, cn, partials);
    mergeA_kernel<<<N / 256, 256, 0, stream>>>(partials, bsum);
    final_kernel<<<1, 64, 0, stream>>>(bsum, out);
}